// Round 2
// baseline (440.458 us; speedup 1.0000x reference)
//
#include <hip/hip_runtime.h>

// EMA: y[b,c,t] = g*y[b,c,t-1] + (1-g)*x[b,c,t],  y[-1]=0, g = weight[c]
// Shapes: B=8, C=512, T=16384 (fp32).  4096 independent rows of length 16384.
//
// One WAVE per row (4 independent waves per 256-thread block): no LDS, no
// __syncthreads -> no vmcnt(0) barrier drains, so the compiler can software-
// pipeline loads across windows. Per window of 256 elems: per-lane 4-elem
// local scan (float4, perfectly coalesced) -> Kogge-Stone wave scan of lane
// carries with uniform factor g^4 -> broadcast window-end value -> scalar
// register carry C (factor g^256). Windows are independent except for the
// single-FMA carry update, so unroll-by-4 gives 4 concurrent load+scan chains.

#define B_ 8
#define C_ 512
#define T_ 16384
#define ROWS_PER_BLOCK 4
#define WIN 256             // elements per wave-iteration (64 lanes * 4)
#define NITER (T_ / WIN)    // 64

__global__ __launch_bounds__(256)
void ema_scan_kernel(const float* __restrict__ x,
                     const float* __restrict__ weight,
                     float* __restrict__ out) {
    const int tid  = threadIdx.x;
    const int lane = tid & 63;
    const int w    = tid >> 6;                       // wave id 0..3
    const int row  = blockIdx.x * ROWS_PER_BLOCK + w; // 0..4095
    const int c    = row & (C_ - 1);

    const float g     = weight[c];
    const float onemg = 1.0f - g;

    // f[k] = g^(4*2^k)
    const float g2 = g * g;
    float f[6];
    f[0] = g2 * g2;
    #pragma unroll
    for (int k = 1; k < 6; ++k) f[k] = f[k - 1] * f[k - 1];
    // lane_factor = g^(4*lane)
    float lane_factor = 1.0f;
    #pragma unroll
    for (int k = 0; k < 6; ++k)
        if (lane & (1 << k)) lane_factor *= f[k];
    const float g256 = f[5] * f[5];

    const float4* __restrict__ xrow = (const float4*)(x   + (size_t)row * T_);
    float4*       __restrict__ orow = (float4*)      (out + (size_t)row * T_);

    float C = 0.0f;   // y value just before the current window

    #pragma unroll 4
    for (int it = 0; it < NITER; ++it) {
        const int vidx = it * 64 + lane;      // float4 index within row
        const float4 X = xrow[vidx];

        // local 4-element scan (zero carry-in)
        const float z0 = onemg * X.x;
        const float z1 = fmaf(g, z0, onemg * X.y);
        const float z2 = fmaf(g, z1, onemg * X.z);
        const float z3 = fmaf(g, z2, onemg * X.w);

        // Kogge-Stone inclusive scan of per-lane carries across the wave:
        // v_l = sum_{m<=l} (g^4)^(l-m) * z3_m
        float v = z3;
        #pragma unroll
        for (int k = 0; k < 6; ++k) {
            const float t = __shfl_up(v, 1 << k, 64);
            if (lane >= (1 << k)) v = fmaf(f[k], t, v);
        }
        // exclusive value: window-relative y at end of previous lane's chunk
        float e = __shfl_up(v, 1, 64);
        if (lane == 0) e = 0.0f;
        // window-end value (window-relative), broadcast from lane 63
        const float E = __shfl(v, 63, 64);

        // absolute carry just before this lane's 4 elements
        const float cth = fmaf(lane_factor, C, e);

        float gp = g * cth;
        float4 Y;
        Y.x = z0 + gp; gp *= g;
        Y.y = z1 + gp; gp *= g;
        Y.z = z2 + gp; gp *= g;
        Y.w = z3 + gp;
        orow[vidx] = Y;

        C = fmaf(g256, C, E);   // exact cross-window carry
    }
}

extern "C" void kernel_launch(void* const* d_in, const int* in_sizes, int n_in,
                              void* d_out, int out_size, void* d_ws, size_t ws_size,
                              hipStream_t stream) {
    const float* x      = (const float*)d_in[0];
    const float* weight = (const float*)d_in[1];
    float* out          = (float*)d_out;
    ema_scan_kernel<<<(B_ * C_) / ROWS_PER_BLOCK, 256, 0, stream>>>(x, weight, out);
}